// Round 6
// baseline (181.053 us; speedup 1.0000x reference)
//
#include <hip/hip_runtime.h>
#include <hip/hip_bf16.h>

typedef __attribute__((ext_vector_type(8))) short bf16x8;
typedef __attribute__((ext_vector_type(4))) float f32x4;
typedef unsigned short u16;

__device__ __forceinline__ u16 f2bf(float f) {
  unsigned int u = __builtin_bit_cast(unsigned int, f);
  u += 0x7fffu + ((u >> 16) & 1u);
  return (u16)(u >> 16);
}
__device__ __forceinline__ float bf2f(unsigned int h) {
  unsigned int u = h << 16;
  return __builtin_bit_cast(float, u);
}

__device__ __forceinline__ void gload_lds16(const void* g, void* l) {
  __builtin_amdgcn_global_load_lds(
      (const __attribute__((address_space(1))) void*)g,
      (__attribute__((address_space(3))) void*)l, 16, 0, 0);
}

#define BAR() __builtin_amdgcn_s_barrier()
#define LGKM0() asm volatile("s_waitcnt lgkmcnt(0)" ::: "memory")
#define LGKM8() asm volatile("s_waitcnt lgkmcnt(8)" ::: "memory")
#define VMC(N) asm volatile("s_waitcnt vmcnt(%0)" ::"n"(N) : "memory")

// ---------------------------------------------------------------------------
// m201-faithful 8-phase GEMM. C[m][n]=sum_k A[m][k]*Bt[n][k]. Tile 256x256.
// 512 thr = 8 waves (2 wr x 4 wc); per-wave 128x64, interleaved stripes:
//   rows wr*64 + mq*128 + mf*16, cols wc*32 + nq*128 + nf*16
// so quadrant (mq,nq) touches exactly LDS A-half mq / B-half nq.
// buf0 = even K-tile, buf1 = odd (fixed). 8 phases/iter, quadrant seq
// (0,0)(0,1)(1,1)(1,0) per K-tile; ds_reads 12/4/8/0; 16 MFMA each.
// Stage 1 half/phase: ph0:buf1.A1(kt1) ph1:A0 ph2:B0 ph3:B1 (buf0,kt+2)
// ph4:buf0.A1 ph5:A0 ph6:B0 ph7:B1 (buf1,kt+3). Every stage overwrites a
// region last read >=2 barriers earlier; vmcnt(6) at ph3/ph7 (post-MFMA)
// gates loads >=4 phases old; last-iter ph3 uses vmcnt(0) (tail gate).
// Swizzle: LDS[row][b16] = global[row][b16^(row&7)]; read applies same XOR
// (0 bank conflicts, measured r1-r5).
// EPI 0: fused QKV proj (Q:*1/32+bq, K:+bk, V:+bv transposed to Vt)
// EPI 2: bf16 row-major out (scores)
// ---------------------------------------------------------------------------
template <int EPI>
__global__ __launch_bounds__(512, 2) void gemm8x(
    const u16* __restrict__ Abase, const u16* __restrict__ Btbase,
    const float* __restrict__ bq, const float* __restrict__ bk,
    const float* __restrict__ bv, void* __restrict__ out0,
    void* __restrict__ out1, void* __restrict__ out2, int Kd, int ldc,
    long long sAz, long long sBz, long long sCz) {
  constexpr int HSZ = 16384;      // half: 128 rows x 64 k x 2B
  constexpr int BUFSZ = 4 * HSZ;  // A0,A1,B0,B1
  __shared__ char lds[2 * BUFSZ];

  const int tid = threadIdx.x;
  const int w = tid >> 6, l = tid & 63;
  const int wr = w >> 2, wc = w & 3;
  const int lq = l >> 4, lr = l & 15;
  const int bm = blockIdx.y * 256, bn = blockIdx.x * 256;
  const int z = blockIdx.z;
  const u16* A = Abase + (size_t)z * sAz;
  const u16* Bt = Btbase + (size_t)z * sBz;
  const int NTk = Kd >> 6, NI = NTk >> 1;

  // staging: dest byte tid*16 (+8192) in a half; source block pre-swizzled
  const int kbp = ((tid & 7) ^ ((tid >> 3) & 7)) * 8;
  const int drow = tid >> 3;
  const u16* gA[2][2];  // [half][u]
  const u16* gB[2][2];
#pragma unroll
  for (int h = 0; h < 2; ++h)
#pragma unroll
    for (int u = 0; u < 2; ++u) {
      gA[h][u] = A + (size_t)(bm + h * 128 + u * 64 + drow) * Kd + kbp;
      gB[h][u] = Bt + (size_t)(bn + h * 128 + u * 64 + drow) * Kd + kbp;
    }

  auto stageA = [&](int buf, int h, int kt) {
    char* d = lds + buf * BUFSZ + h * HSZ + tid * 16;
    gload_lds16(gA[h][0] + kt * 64, d);
    gload_lds16(gA[h][1] + kt * 64, d + 8192);
  };
  auto stageB = [&](int buf, int h, int kt) {
    char* d = lds + buf * BUFSZ + (2 + h) * HSZ + tid * 16;
    gload_lds16(gB[h][0] + kt * 64, d);
    gload_lds16(gB[h][1] + kt * 64, d + 8192);
  };

  const int rA = wr * 64 + lr;
  const int rB = wc * 32 + lr;
  int aoff[2], boff[2];
#pragma unroll
  for (int kh = 0; kh < 2; ++kh) {
    aoff[kh] = rA * 128 + (((kh * 4 + lq) ^ (rA & 7)) << 4);
    boff[kh] = rB * 128 + (((kh * 4 + lq) ^ (rB & 7)) << 4);
  }

  f32x4 acc[2][4][2][2] = {};  // [mq][mf][nq][nf]
  bf16x8 a[2][4];              // [kh][mf] current A-half
  bf16x8 bb[2][2][2];          // [nq][kh][nf] both B-halves live

#define RD_A(BUF, MQ)                                                       \
  {                                                                         \
    const char* p_ = lds + (BUF)*BUFSZ + (MQ)*HSZ;                          \
    _Pragma("unroll") for (int kh = 0; kh < 2; ++kh)                        \
        _Pragma("unroll") for (int mf = 0; mf < 4; ++mf) a[kh][mf] =        \
            *(const bf16x8*)(p_ + aoff[kh] + mf * 2048);                    \
  }
#define RD_B(BUF, NQ)                                                       \
  {                                                                         \
    const char* p_ = lds + (BUF)*BUFSZ + (2 + (NQ)) * HSZ;                  \
    _Pragma("unroll") for (int kh = 0; kh < 2; ++kh)                        \
        _Pragma("unroll") for (int nf = 0; nf < 2; ++nf) bb[NQ][kh][nf] =   \
            *(const bf16x8*)(p_ + boff[kh] + nf * 2048);                    \
  }
#define MMAQ(MQ, NQ)                                                          \
  {                                                                           \
    __builtin_amdgcn_s_setprio(1);                                            \
    _Pragma("unroll") for (int kh = 0; kh < 2; ++kh)                          \
        _Pragma("unroll") for (int mf = 0; mf < 4; ++mf)                      \
            _Pragma("unroll") for (int nf = 0; nf < 2; ++nf) acc[MQ][mf][NQ]  \
                [nf] = __builtin_amdgcn_mfma_f32_16x16x32_bf16(               \
                    a[kh][mf], bb[NQ][kh][nf], acc[MQ][mf][NQ][nf], 0, 0, 0); \
    __builtin_amdgcn_s_setprio(0);                                            \
  }

  // prologue: kt0 full into buf0, kt1 {A0,B0,B1} into buf1
  stageA(0, 0, 0);
  stageB(0, 0, 0);
  stageB(0, 1, 0);
  stageA(0, 1, 0);
  stageA(1, 0, 1);
  stageB(1, 0, 1);
  stageB(1, 1, 1);
  VMC(6);
  BAR();

  for (int i = 0; i < NI; ++i) {
    const int kt1 = 2 * i + 1, ktn0 = 2 * i + 2, ktn1 = 2 * i + 3;
    const bool s0 = ktn0 < NTk, s1 = ktn1 < NTk;
    // ph0: buf0 q(0,0); stage buf1.A1 <- kt1
    RD_A(0, 0);
    RD_B(0, 0);
    stageA(1, 1, kt1);
    LGKM8();
    BAR();
    LGKM0();
    MMAQ(0, 0);
    BAR();
    // ph1: q(0,1); stage buf0.A0 <- ktn0
    RD_B(0, 1);
    if (s0) stageA(0, 0, ktn0);
    BAR();
    LGKM0();
    MMAQ(0, 1);
    BAR();
    // ph2: q(1,1); stage buf0.B0
    RD_A(0, 1);
    if (s0) stageB(0, 0, ktn0);
    BAR();
    LGKM0();
    MMAQ(1, 1);
    BAR();
    // ph3: q(1,0) regs-only; stage buf0.B1; K-tile gate
    if (s0) stageB(0, 1, ktn0);
    BAR();
    MMAQ(1, 0);
    if (i + 1 < NI) VMC(6); else VMC(0);
    BAR();
    // ph4: buf1 q(0,0); stage buf0.A1
    RD_A(1, 0);
    RD_B(1, 0);
    if (s0) stageA(0, 1, ktn0);
    LGKM8();
    BAR();
    LGKM0();
    MMAQ(0, 0);
    BAR();
    // ph5: q(0,1); stage buf1.A0 <- ktn1
    RD_B(1, 1);
    if (s1) stageA(1, 0, ktn1);
    BAR();
    LGKM0();
    MMAQ(0, 1);
    BAR();
    // ph6: q(1,1); stage buf1.B0
    RD_A(1, 1);
    if (s1) stageB(1, 0, ktn1);
    BAR();
    LGKM0();
    MMAQ(1, 1);
    BAR();
    // ph7: q(1,0); stage buf1.B1; gate
    if (s1) stageB(1, 1, ktn1);
    BAR();
    MMAQ(1, 0);
    VMC(6);
    BAR();
  }

  // epilogue. C/D frag: col = lane&15, row = (lane>>4)*4 + e  [m89]
  if constexpr (EPI == 0) {
    const int mat = bn >> 10;
    const float sc = (mat == 0) ? 0.03125f : 1.0f;
    const float* bias = (mat == 0) ? bq : (mat == 1 ? bk : bv);
    u16* Q = (u16*)out0;
    u16* K = (u16*)out1;
    u16* V = (u16*)out2;
#pragma unroll
    for (int nq = 0; nq < 2; ++nq)
#pragma unroll
      for (int nf = 0; nf < 2; ++nf) {
        const int oc = ((bn + wc * 32 + nq * 128 + nf * 16 + lr) & 1023);
        const float bv2 = bias[oc];
#pragma unroll
        for (int mq = 0; mq < 2; ++mq)
#pragma unroll
          for (int mf = 0; mf < 4; ++mf) {
            const int row = bm + wr * 64 + mq * 128 + mf * 16 + lq * 4;
            if (mat < 2) {
              u16* dst = (mat == 0) ? Q : K;
#pragma unroll
              for (int e = 0; e < 4; ++e)
                dst[(size_t)(row + e) * 1024 + oc] =
                    f2bf((acc[mq][mf][nq][nf][e] + bv2) * sc);
            } else {
              const int bz = row >> 11, sdx = row & 2047;
              ushort4 pk;
              pk.x = f2bf(acc[mq][mf][nq][nf][0] + bv2);
              pk.y = f2bf(acc[mq][mf][nq][nf][1] + bv2);
              pk.z = f2bf(acc[mq][mf][nq][nf][2] + bv2);
              pk.w = f2bf(acc[mq][mf][nq][nf][3] + bv2);
              *(ushort4*)&V[((size_t)bz * 1024 + oc) * 2048 + sdx] = pk;
            }
          }
      }
  } else {
    u16* C = (u16*)out0 + (size_t)z * sCz;
#pragma unroll
    for (int nq = 0; nq < 2; ++nq)
#pragma unroll
      for (int nf = 0; nf < 2; ++nf) {
        const int col = bn + wc * 32 + nq * 128 + nf * 16 + lr;
#pragma unroll
        for (int mq = 0; mq < 2; ++mq)
#pragma unroll
          for (int mf = 0; mf < 4; ++mf) {
            const int row = bm + wr * 64 + mq * 128 + mf * 16 + lq * 4;
#pragma unroll
            for (int e = 0; e < 4; ++e)
              C[(size_t)(row + e) * ldc + col] = f2bf(acc[mq][mf][nq][nf][e]);
          }
      }
  }
#undef RD_A
#undef RD_B
#undef MMAQ
}

// ---------------------------------------------------------------------------
// PV GEMM: 128x256 tile, 2 phases/K-tile, A dbuf (2x16KB) + B 3-slot ring
// (3x32KB) = 128KB. Per-wave 64x64 (2 wr x 4 wc). Stage lead 2 K-tiles;
// gates: vmcnt(6) per K-tile end (newest = this tile's 6 loads), vmcnt(0)
// at t>=NT-2. f32 row-major out.
// ---------------------------------------------------------------------------
__global__ __launch_bounds__(512, 2) void gemm2v(
    const u16* __restrict__ Abase, const u16* __restrict__ Btbase,
    float* __restrict__ outp, int Kd, int ldc, long long sAz, long long sBz,
    long long sCz) {
  constexpr int ASZ = 16384;          // A tile: 128 x 64 x 2B
  constexpr int BSZ = 32768;          // B tile: 256 x 64 x 2B
  constexpr int BBASE = 2 * ASZ;
  __shared__ char lds[2 * ASZ + 3 * BSZ];

  const int tid = threadIdx.x;
  const int w = tid >> 6, l = tid & 63;
  const int wr = w >> 2, wc = w & 3;
  const int lq = l >> 4, lr = l & 15;
  const int bm = blockIdx.y * 128, bn = blockIdx.x * 256;
  const int z = blockIdx.z;
  const u16* A = Abase + (size_t)z * sAz;
  const u16* Bt = Btbase + (size_t)z * sBz;
  const int NT = Kd >> 6;

  const int kbp = ((tid & 7) ^ ((tid >> 3) & 7)) * 8;
  const int drow = tid >> 3;
  const u16* gA[2];
  const u16* gB[4];
#pragma unroll
  for (int u = 0; u < 2; ++u)
    gA[u] = A + (size_t)(bm + u * 64 + drow) * Kd + kbp;
#pragma unroll
  for (int u = 0; u < 4; ++u)
    gB[u] = Bt + (size_t)(bn + u * 64 + drow) * Kd + kbp;

  auto stageA = [&](int kt) {
    char* d = lds + (kt & 1) * ASZ + tid * 16;
#pragma unroll
    for (int u = 0; u < 2; ++u) gload_lds16(gA[u] + kt * 64, d + u * 8192);
  };
  auto stageB = [&](int kt) {
    char* d = lds + BBASE + (kt % 3) * BSZ + tid * 16;
#pragma unroll
    for (int u = 0; u < 4; ++u) gload_lds16(gB[u] + kt * 64, d + u * 8192);
  };

  const int rA = wr * 64 + lr;
  const int rB0 = wc * 64 + lr;
  int aoff[2];
#pragma unroll
  for (int kh = 0; kh < 2; ++kh)
    aoff[kh] = rA * 128 + (((kh * 4 + lq) ^ (rA & 7)) << 4);

  f32x4 acc[4][2][2] = {};  // [mf][nh][nf]
  bf16x8 a[2][4], b[2][2];  // a[kh][mf]; b[kh][nf] current nh

  auto rdA = [&](int kt) {
    const char* p = lds + (kt & 1) * ASZ;
#pragma unroll
    for (int kh = 0; kh < 2; ++kh)
#pragma unroll
      for (int mf = 0; mf < 4; ++mf)
        a[kh][mf] = *(const bf16x8*)(p + aoff[kh] + mf * 2048);
  };
  auto rdB = [&](int kt, int nh) {
    const char* p = lds + BBASE + (kt % 3) * BSZ;
    const int rB = rB0 + nh * 32;
#pragma unroll
    for (int kh = 0; kh < 2; ++kh) {
      const int o = rB * 128 + (((kh * 4 + lq) ^ (rB & 7)) << 4);
#pragma unroll
      for (int nf = 0; nf < 2; ++nf)
        b[kh][nf] = *(const bf16x8*)(p + o + nf * 2048);
    }
  };
  auto mma = [&](int nh) {
    __builtin_amdgcn_s_setprio(1);
#pragma unroll
    for (int kh = 0; kh < 2; ++kh)
#pragma unroll
      for (int mf = 0; mf < 4; ++mf)
#pragma unroll
        for (int nf = 0; nf < 2; ++nf)
          acc[mf][nh][nf] = __builtin_amdgcn_mfma_f32_16x16x32_bf16(
              a[kh][mf], b[kh][nf], acc[mf][nh][nf], 0, 0, 0);
    __builtin_amdgcn_s_setprio(0);
  };

  // prologue: B(0), A(0), B(1), A(1); newest 6 = B(1)+A(1)
  stageB(0);
  stageA(0);
  stageB(1);
  stageA(1);
  VMC(6);
  BAR();

  for (int t = 0; t < NT; ++t) {
    // ph0: reads A(t), B(t) nh0 (12 reads); stage B(t+2)
    rdA(t);
    rdB(t, 0);
    if (t + 2 < NT) stageB(t + 2);
    LGKM8();
    BAR();
    LGKM0();
    mma(0);
    BAR();
    // ph1: reads B(t) nh1 (4); stage A(t+2); K-tile gate
    rdB(t, 1);
    if (t + 2 < NT) stageA(t + 2);
    BAR();
    LGKM0();
    mma(1);
    if (t + 3 <= NT) VMC(6); else VMC(0);
    BAR();
  }

  float* C = outp + (size_t)z * sCz;
#pragma unroll
  for (int nh = 0; nh < 2; ++nh)
#pragma unroll
    for (int nf = 0; nf < 2; ++nf) {
      const int col = bn + wc * 64 + nh * 32 + nf * 16 + lr;
#pragma unroll
      for (int mf = 0; mf < 4; ++mf) {
        const int row = bm + wr * 64 + mf * 16 + lq * 4;
#pragma unroll
        for (int e = 0; e < 4; ++e)
          C[(size_t)(row + e) * ldc + col] = acc[mf][nh][nf][e];
      }
    }
}

// ---------------------------------------------------------------------------
__global__ __launch_bounds__(256) void cvt_x(const float* __restrict__ in,
                                             u16* __restrict__ out) {
  const int i = blockIdx.x * 256 + threadIdx.x;
  const float4 v = ((const float4*)in)[i];
  ushort4 o;
  o.x = f2bf(v.x);
  o.y = f2bf(v.y);
  o.z = f2bf(v.z);
  o.w = f2bf(v.w);
  ((ushort4*)out)[i] = o;
}

// W [1024 in][1024 out] f32 -> Wt [1024 out][1024 in] bf16, z selects q/k/v
__global__ void cvt_wt(const float* __restrict__ Wq,
                       const float* __restrict__ Wk,
                       const float* __restrict__ Wv, u16* __restrict__ Wt) {
  __shared__ float s[32][33];
  const float* W = blockIdx.z == 0 ? Wq : (blockIdx.z == 1 ? Wk : Wv);
  u16* O = Wt + (size_t)blockIdx.z * 1048576;
  const int k0 = blockIdx.y * 32, n0 = blockIdx.x * 32;
  s[threadIdx.y][threadIdx.x] =
      W[(size_t)(k0 + threadIdx.y) * 1024 + n0 + threadIdx.x];
  __syncthreads();
  O[(size_t)(n0 + threadIdx.y) * 1024 + k0 + threadIdx.x] =
      f2bf(s[threadIdx.x][threadIdx.y]);
}

// in-place row softmax over bf16 [4][2048][2048]; one block per row
__global__ __launch_bounds__(256) void softmax_rows(u16* __restrict__ SP) {
  const size_t base = ((size_t)blockIdx.y * 2048 + blockIdx.x) * 2048;
  u16* p = SP + base;
  const int t = threadIdx.x;
  __shared__ float red[4];

  uint4 u = ((const uint4*)p)[t];  // 8 bf16 per thread
  unsigned int uu[4] = {u.x, u.y, u.z, u.w};
  float f[8];
#pragma unroll
  for (int j = 0; j < 4; ++j) {
    f[2 * j] = bf2f(uu[j] & 0xffffu);
    f[2 * j + 1] = __builtin_bit_cast(float, uu[j] & 0xffff0000u);
  }
  float mx = f[0];
#pragma unroll
  for (int i = 1; i < 8; ++i) mx = fmaxf(mx, f[i]);
#pragma unroll
  for (int o = 32; o; o >>= 1) mx = fmaxf(mx, __shfl_xor(mx, o, 64));
  if ((t & 63) == 0) red[t >> 6] = mx;
  __syncthreads();
  mx = fmaxf(fmaxf(red[0], red[1]), fmaxf(red[2], red[3]));
  __syncthreads();

  float e[8];
  float sum = 0.f;
#pragma unroll
  for (int i = 0; i < 8; ++i) {
    e[i] = __expf(f[i] - mx);
    sum += e[i];
  }
#pragma unroll
  for (int o = 32; o; o >>= 1) sum += __shfl_xor(sum, o, 64);
  if ((t & 63) == 0) red[t >> 6] = sum;
  __syncthreads();
  sum = red[0] + red[1] + red[2] + red[3];
  const float inv = 1.0f / sum;

  uint4 ov;
  unsigned int w0[4];
#pragma unroll
  for (int j = 0; j < 4; ++j) {
    unsigned int lo = f2bf(e[2 * j] * inv);
    unsigned int hi = f2bf(e[2 * j + 1] * inv);
    w0[j] = lo | (hi << 16);
  }
  ov.x = w0[0];
  ov.y = w0[1];
  ov.z = w0[2];
  ov.w = w0[3];
  ((uint4*)p)[t] = ov;
}

// ---------------------------------------------------------------------------
extern "C" void kernel_launch(void* const* d_in, const int* in_sizes, int n_in,
                              void* d_out, int out_size, void* d_ws,
                              size_t ws_size, hipStream_t stream) {
  const float* x = (const float*)d_in[0];
  const float* Wq = (const float*)d_in[1];
  const float* bq = (const float*)d_in[2];
  const float* Wk = (const float*)d_in[3];
  const float* bk = (const float*)d_in[4];
  const float* Wv = (const float*)d_in[5];
  const float* bv = (const float*)d_in[6];
  float* out = (float*)d_out;
  char* ws = (char*)d_ws;

  u16* xb = (u16*)ws;                    // 16 MiB [8192][1024]
  u16* Wt = (u16*)(ws + 16777216);       // 6 MiB  [3072][1024]
  u16* Qb = (u16*)(ws + 23068672);       // 16 MiB [8192][1024]
  u16* Kb = Qb + 8388608;                // 16 MiB
  u16* Vt = Kb + 8388608;                // 16 MiB [4][1024][2048]
  u16* SP = Vt + 8388608;                // 32 MiB [4][2048][2048]

  // 1) dtype prep
  cvt_x<<<8192, 256, 0, stream>>>(x, xb);
  cvt_wt<<<dim3(32, 32, 3), dim3(32, 32), 0, stream>>>(Wq, Wk, Wv, Wt);

  // 2) fused QKV projection (N=3072; Q scaled 1/32 in epilogue)
  gemm8x<0><<<dim3(12, 32, 1), 512, 0, stream>>>(
      xb, Wt, bq, bk, bv, Qb, Kb, Vt, 1024, 0, 0, 0, 0);

  // 3) scores = Qs . K^T  (bf16 out, per batch)
  gemm8x<2><<<dim3(8, 8, 4), 512, 0, stream>>>(
      Qb, Kb, nullptr, nullptr, nullptr, SP, nullptr, nullptr, 1024, 2048,
      2097152LL, 2097152LL, 4194304LL);

  // 4) softmax in place
  softmax_rows<<<dim3(2048, 4), 256, 0, stream>>>(SP);

  // 5) out = P . V   (A = P [2048][2048], Bt = Vt [1024][2048])
  gemm2v<<<dim3(4, 16, 4), 512, 0, stream>>>(
      SP, Vt, out, 2048, 1024, 4194304LL, 2097152LL, 2097152LL);
}

// Round 7
// 176.999 us; speedup vs baseline: 1.0229x; 1.0229x over previous
//
#include <hip/hip_runtime.h>
#include <hip/hip_bf16.h>

typedef __attribute__((ext_vector_type(8))) short bf16x8;
typedef __attribute__((ext_vector_type(4))) float f32x4;
typedef unsigned short u16;

__device__ __forceinline__ u16 f2bf(float f) {
  unsigned int u = __builtin_bit_cast(unsigned int, f);
  u += 0x7fffu + ((u >> 16) & 1u);
  return (u16)(u >> 16);
}
__device__ __forceinline__ float bf2f(unsigned int h) {
  unsigned int u = h << 16;
  return __builtin_bit_cast(float, u);
}

__device__ __forceinline__ void gload_lds16(const void* g, void* l) {
  __builtin_amdgcn_global_load_lds(
      (const __attribute__((address_space(1))) void*)g,
      (__attribute__((address_space(3))) void*)l, 16, 0, 0);
}

#define BAR() __builtin_amdgcn_s_barrier()
#define VMC(N) asm volatile("s_waitcnt vmcnt(%0)" ::"n"(N) : "memory")

// ---------------------------------------------------------------------------
// Reg-pipelined 256x256 NT GEMM. C[m][n]=sum_k A[m][k]*Bt[n][k].
// 512 thr = 8 waves (2 wr x 4 wc); per-wave 128x64 interleaved stripes:
//   rows wr*64 + mq*128 + mf*16, cols wc*32 + nq*128 + nf*16.
// K-tile 64, dbuf. 4 phases/tile = quadrants (0,0)(0,1)(1,1)(1,0); MFMA
// consumes regs issued >=1 phase earlier (aE,aO,bb[2] sets; compiler emits
// counted lgkm waits). ONE barrier/phase. Stage 1 half (2 gloads)/phase:
// q0:A1(t+1) q1:A0(t+2) q2:B0(t+2) q3:B1(t+2) (regions freed >=1 barrier
// prior). Gate: top-of-phase vmcnt(6) — lands units staged >=4 phases ago
// (min stage->read lag 5 phases, so no stall); vmcnt(0) in last 2 tiles.
// Swizzle: LDS[row][b16] = global[row][b16^(row&7)], reads apply same XOR
// (0 conflicts, r1-r6).  EPI 0: fused QKV proj; EPI 2: bf16 scores out.
// ---------------------------------------------------------------------------
template <int EPI>
__global__ __launch_bounds__(512, 2) void gemm8x(
    const u16* __restrict__ Abase, const u16* __restrict__ Btbase,
    const float* __restrict__ bq, const float* __restrict__ bk,
    const float* __restrict__ bv, void* __restrict__ out0,
    void* __restrict__ out1, void* __restrict__ out2, int Kd, int ldc,
    long long sAz, long long sBz, long long sCz) {
  constexpr int HSZ = 16384;      // half: 128 rows x 64 k x 2B
  constexpr int BUFSZ = 4 * HSZ;  // A0,A1,B0,B1
  __shared__ char lds[2 * BUFSZ];

  const int tid = threadIdx.x;
  const int w = tid >> 6, l = tid & 63;
  const int wr = w >> 2, wc = w & 3;
  const int lq = l >> 4, lr = l & 15;
  const int bm = blockIdx.y * 256, bn = blockIdx.x * 256;
  const int z = blockIdx.z;
  const u16* A = Abase + (size_t)z * sAz;
  const u16* Bt = Btbase + (size_t)z * sBz;
  const int NTk = Kd >> 6;

  // staging: dest byte tid*16 (+8192) in a half; source block pre-swizzled
  const int kbp = ((tid & 7) ^ ((tid >> 3) & 7)) * 8;
  const int drow = tid >> 3;
  const u16* gA[2][2];
  const u16* gB[2][2];
#pragma unroll
  for (int h = 0; h < 2; ++h)
#pragma unroll
    for (int u = 0; u < 2; ++u) {
      gA[h][u] = A + (size_t)(bm + h * 128 + u * 64 + drow) * Kd + kbp;
      gB[h][u] = Bt + (size_t)(bn + h * 128 + u * 64 + drow) * Kd + kbp;
    }

  auto stageA = [&](int buf, int h, int kt) {
    char* d = lds + buf * BUFSZ + h * HSZ + tid * 16;
    gload_lds16(gA[h][0] + kt * 64, d);
    gload_lds16(gA[h][1] + kt * 64, d + 8192);
  };
  auto stageB = [&](int buf, int h, int kt) {
    char* d = lds + buf * BUFSZ + (2 + h) * HSZ + tid * 16;
    gload_lds16(gB[h][0] + kt * 64, d);
    gload_lds16(gB[h][1] + kt * 64, d + 8192);
  };

  const int rA = wr * 64 + lr;
  const int rB = wc * 32 + lr;
  int aoff[2], boff[2];
#pragma unroll
  for (int kh = 0; kh < 2; ++kh) {
    aoff[kh] = rA * 128 + (((kh * 4 + lq) ^ (rA & 7)) << 4);
    boff[kh] = rB * 128 + (((kh * 4 + lq) ^ (rB & 7)) << 4);
  }

  f32x4 acc[2][4][2][2] = {};  // [mq][mf][nq][nf]
  bf16x8 aE[2][4], aO[2][4];   // A0 / A1 fragment sets [kh][mf]
  bf16x8 bb[2][2][2];          // [nq][kh][nf]

#define RD_AE(BUF)                                                        \
  {                                                                       \
    const char* p_ = lds + (BUF)*BUFSZ;                                   \
    _Pragma("unroll") for (int kh = 0; kh < 2; ++kh)                      \
        _Pragma("unroll") for (int mf = 0; mf < 4; ++mf) aE[kh][mf] =     \
            *(const bf16x8*)(p_ + aoff[kh] + mf * 2048);                  \
  }
#define RD_AO(BUF)                                                        \
  {                                                                       \
    const char* p_ = lds + (BUF)*BUFSZ + HSZ;                             \
    _Pragma("unroll") for (int kh = 0; kh < 2; ++kh)                      \
        _Pragma("unroll") for (int mf = 0; mf < 4; ++mf) aO[kh][mf] =     \
            *(const bf16x8*)(p_ + aoff[kh] + mf * 2048);                  \
  }
#define RD_B(BUF, NQ)                                                     \
  {                                                                       \
    const char* p_ = lds + (BUF)*BUFSZ + (2 + (NQ)) * HSZ;                \
    _Pragma("unroll") for (int kh = 0; kh < 2; ++kh)                      \
        _Pragma("unroll") for (int nf = 0; nf < 2; ++nf) bb[NQ][kh][nf] = \
            *(const bf16x8*)(p_ + boff[kh] + nf * 2048);                  \
  }
#define MMAQ(MQ, NQ, ASET)                                                    \
  {                                                                           \
    __builtin_amdgcn_s_setprio(1);                                            \
    _Pragma("unroll") for (int kh = 0; kh < 2; ++kh)                          \
        _Pragma("unroll") for (int mf = 0; mf < 4; ++mf)                      \
            _Pragma("unroll") for (int nf = 0; nf < 2; ++nf) acc[MQ][mf][NQ]  \
                [nf] = __builtin_amdgcn_mfma_f32_16x16x32_bf16(               \
                    ASET[kh][mf], bb[NQ][kh][nf], acc[MQ][mf][NQ][nf], 0, 0,  \
                    0);                                                       \
    __builtin_amdgcn_s_setprio(0);                                            \
  }

  // prologue: tile0 all 4 halves, tile1 {A0,B0,B1}; A1(1) staged at q0(0)
  stageA(0, 0, 0);
  stageB(0, 0, 0);
  stageB(0, 1, 0);
  stageA(0, 1, 0);
  stageA(1, 0, 1);
  stageB(1, 0, 1);
  stageB(1, 1, 1);
  VMC(6);
  BAR();

  for (int t = 0; t < NTk; ++t) {
    const int buf = t & 1;
    const bool deep = (t + 2 < NTk);
    // q0: read A0,B0,B1 (16); stage A1(t+1); MMA(0,0)
    if (deep) VMC(6); else VMC(0);
    RD_AE(buf);
    RD_B(buf, 0);
    RD_B(buf, 1);
    if (t + 1 < NTk) stageA(buf ^ 1, 1, t + 1);
    BAR();
    MMAQ(0, 0, aE);
    // q1: read A1 (8); stage A0(t+2); MMA(0,1)
    if (deep) VMC(6); else VMC(0);
    RD_AO(buf);
    if (deep) stageA(buf, 0, t + 2);
    BAR();
    MMAQ(0, 1, aE);
    // q2: stage B0(t+2); MMA(1,1)
    if (deep) VMC(6); else VMC(0);
    if (deep) stageB(buf, 0, t + 2);
    BAR();
    MMAQ(1, 1, aO);
    // q3: stage B1(t+2); MMA(1,0)
    if (deep) VMC(6); else VMC(0);
    if (deep) stageB(buf, 1, t + 2);
    BAR();
    MMAQ(1, 0, aO);
  }

  // epilogue. C/D frag: col = lane&15, row = (lane>>4)*4 + e  [m89]
  if constexpr (EPI == 0) {
    const int mat = bn >> 10;
    const float sc = (mat == 0) ? 0.03125f : 1.0f;
    const float* bias = (mat == 0) ? bq : (mat == 1 ? bk : bv);
    u16* Q = (u16*)out0;
    u16* K = (u16*)out1;
    u16* V = (u16*)out2;
#pragma unroll
    for (int nq = 0; nq < 2; ++nq)
#pragma unroll
      for (int nf = 0; nf < 2; ++nf) {
        const int oc = ((bn + wc * 32 + nq * 128 + nf * 16 + lr) & 1023);
        const float bv2 = bias[oc];
#pragma unroll
        for (int mq = 0; mq < 2; ++mq)
#pragma unroll
          for (int mf = 0; mf < 4; ++mf) {
            const int row = bm + wr * 64 + mq * 128 + mf * 16 + lq * 4;
            if (mat < 2) {
              u16* dst = (mat == 0) ? Q : K;
#pragma unroll
              for (int e = 0; e < 4; ++e)
                dst[(size_t)(row + e) * 1024 + oc] =
                    f2bf((acc[mq][mf][nq][nf][e] + bv2) * sc);
            } else {
              const int bz = row >> 11, sdx = row & 2047;
              ushort4 pk;
              pk.x = f2bf(acc[mq][mf][nq][nf][0] + bv2);
              pk.y = f2bf(acc[mq][mf][nq][nf][1] + bv2);
              pk.z = f2bf(acc[mq][mf][nq][nf][2] + bv2);
              pk.w = f2bf(acc[mq][mf][nq][nf][3] + bv2);
              *(ushort4*)&V[((size_t)bz * 1024 + oc) * 2048 + sdx] = pk;
            }
          }
      }
  } else {
    u16* C = (u16*)out0 + (size_t)z * sCz;
#pragma unroll
    for (int nq = 0; nq < 2; ++nq)
#pragma unroll
      for (int nf = 0; nf < 2; ++nf) {
        const int col = bn + wc * 32 + nq * 128 + nf * 16 + lr;
#pragma unroll
        for (int mq = 0; mq < 2; ++mq)
#pragma unroll
          for (int mf = 0; mf < 4; ++mf) {
            const int row = bm + wr * 64 + mq * 128 + mf * 16 + lq * 4;
#pragma unroll
            for (int e = 0; e < 4; ++e)
              C[(size_t)(row + e) * ldc + col] = f2bf(acc[mq][mf][nq][nf][e]);
          }
      }
  }
#undef RD_AE
#undef RD_AO
#undef RD_B
#undef MMAQ
}

// ---------------------------------------------------------------------------
// Reg-pipelined PV GEMM: 128x256 tile, 2 phases/K-tile. A dbuf (2x16KB) +
// B 3-slot ring (3x32KB) = 128KB. Per-wave 64x64 (2 wr x 4 wc). All 16
// fragment reads issued at ph0 (kh0 self-stalls once/tile, kh1 pipelined);
// stage B(t+2)@ph0, A(t+2)@ph1; gate vmcnt(4) at ph1-top (lands A,B(t+1),
// staged 2-3 phases prior), vmcnt(0) in tail. ONE barrier/phase.
// ---------------------------------------------------------------------------
__global__ __launch_bounds__(512, 2) void gemm2v(
    const u16* __restrict__ Abase, const u16* __restrict__ Btbase,
    float* __restrict__ outp, int Kd, int ldc, long long sAz, long long sBz,
    long long sCz) {
  constexpr int ASZ = 16384;
  constexpr int BSZ = 32768;
  constexpr int BBASE = 2 * ASZ;
  __shared__ char lds[2 * ASZ + 3 * BSZ];

  const int tid = threadIdx.x;
  const int w = tid >> 6, l = tid & 63;
  const int wr = w >> 2, wc = w & 3;
  const int lq = l >> 4, lr = l & 15;
  const int bm = blockIdx.y * 128, bn = blockIdx.x * 256;
  const int z = blockIdx.z;
  const u16* A = Abase + (size_t)z * sAz;
  const u16* Bt = Btbase + (size_t)z * sBz;
  const int NT = Kd >> 6;

  const int kbp = ((tid & 7) ^ ((tid >> 3) & 7)) * 8;
  const int drow = tid >> 3;
  const u16* gA[2];
  const u16* gB[4];
#pragma unroll
  for (int u = 0; u < 2; ++u)
    gA[u] = A + (size_t)(bm + u * 64 + drow) * Kd + kbp;
#pragma unroll
  for (int u = 0; u < 4; ++u)
    gB[u] = Bt + (size_t)(bn + u * 64 + drow) * Kd + kbp;

  auto stageA = [&](int kt) {
    char* d = lds + (kt & 1) * ASZ + tid * 16;
#pragma unroll
    for (int u = 0; u < 2; ++u) gload_lds16(gA[u] + kt * 64, d + u * 8192);
  };
  auto stageB = [&](int kt) {
    char* d = lds + BBASE + (kt % 3) * BSZ + tid * 16;
#pragma unroll
    for (int u = 0; u < 4; ++u) gload_lds16(gB[u] + kt * 64, d + u * 8192);
  };

  const int rA = wr * 64 + lr;
  const int rB0 = wc * 64 + lr;
  int aoff[2];
#pragma unroll
  for (int kh = 0; kh < 2; ++kh)
    aoff[kh] = rA * 128 + (((kh * 4 + lq) ^ (rA & 7)) << 4);

  f32x4 acc[4][2][2] = {};   // [mf][nh][nf]
  bf16x8 a[2][4];            // [kh][mf]
  bf16x8 bb[2][2][2];        // [nh][kh][nf]

  auto rdA = [&](int kt) {
    const char* p = lds + (kt & 1) * ASZ;
#pragma unroll
    for (int kh = 0; kh < 2; ++kh)
#pragma unroll
      for (int mf = 0; mf < 4; ++mf)
        a[kh][mf] = *(const bf16x8*)(p + aoff[kh] + mf * 2048);
  };
  auto rdB = [&](int kt) {
    const char* p = lds + BBASE + (kt % 3) * BSZ;
#pragma unroll
    for (int nh = 0; nh < 2; ++nh) {
      const int rB = rB0 + nh * 32;
#pragma unroll
      for (int kh = 0; kh < 2; ++kh) {
        const int o = rB * 128 + (((kh * 4 + lq) ^ (rB & 7)) << 4);
#pragma unroll
        for (int nf = 0; nf < 2; ++nf)
          bb[nh][kh][nf] = *(const bf16x8*)(p + o + nf * 2048);
      }
    }
  };
  auto mma = [&](int kh) {
    __builtin_amdgcn_s_setprio(1);
#pragma unroll
    for (int nh = 0; nh < 2; ++nh)
#pragma unroll
      for (int mf = 0; mf < 4; ++mf)
#pragma unroll
        for (int nf = 0; nf < 2; ++nf)
          acc[mf][nh][nf] = __builtin_amdgcn_mfma_f32_16x16x32_bf16(
              a[kh][mf], bb[nh][kh][nf], acc[mf][nh][nf], 0, 0, 0);
    __builtin_amdgcn_s_setprio(0);
  };

  // prologue: B(0), A(0), B(1), A(1); vmcnt(6) -> tile0 landed
  stageB(0);
  stageA(0);
  stageB(1);
  stageA(1);
  VMC(6);
  BAR();

  for (int t = 0; t < NT; ++t) {
    // ph0: all 16 reads of tile t; stage B(t+2)
    rdA(t);
    rdB(t);
    if (t + 2 < NT) stageB(t + 2);
    BAR();
    mma(0);
    // ph1: stage A(t+2); gate for tile t+1
    if (t + 2 < NT) VMC(4); else VMC(0);
    if (t + 2 < NT) stageA(t + 2);
    BAR();
    mma(1);
  }

  float* C = outp + (size_t)z * sCz;
#pragma unroll
  for (int nh = 0; nh < 2; ++nh)
#pragma unroll
    for (int nf = 0; nf < 2; ++nf) {
      const int col = bn + wc * 64 + nh * 32 + nf * 16 + lr;
#pragma unroll
      for (int mf = 0; mf < 4; ++mf) {
        const int row = bm + wr * 64 + mf * 16 + lq * 4;
#pragma unroll
        for (int e = 0; e < 4; ++e)
          C[(size_t)(row + e) * ldc + col] = acc[mf][nh][nf][e];
      }
    }
}

// ---------------------------------------------------------------------------
__global__ __launch_bounds__(256) void cvt_x(const float* __restrict__ in,
                                             u16* __restrict__ out) {
  const int i = blockIdx.x * 256 + threadIdx.x;
  const float4 v = ((const float4*)in)[i];
  ushort4 o;
  o.x = f2bf(v.x);
  o.y = f2bf(v.y);
  o.z = f2bf(v.z);
  o.w = f2bf(v.w);
  ((ushort4*)out)[i] = o;
}

// W [1024 in][1024 out] f32 -> Wt [1024 out][1024 in] bf16, z selects q/k/v
__global__ void cvt_wt(const float* __restrict__ Wq,
                       const float* __restrict__ Wk,
                       const float* __restrict__ Wv, u16* __restrict__ Wt) {
  __shared__ float s[32][33];
  const float* W = blockIdx.z == 0 ? Wq : (blockIdx.z == 1 ? Wk : Wv);
  u16* O = Wt + (size_t)blockIdx.z * 1048576;
  const int k0 = blockIdx.y * 32, n0 = blockIdx.x * 32;
  s[threadIdx.y][threadIdx.x] =
      W[(size_t)(k0 + threadIdx.y) * 1024 + n0 + threadIdx.x];
  __syncthreads();
  O[(size_t)(n0 + threadIdx.y) * 1024 + k0 + threadIdx.x] =
      f2bf(s[threadIdx.x][threadIdx.y]);
}

// in-place row softmax over bf16 [4][2048][2048]; one block per row
__global__ __launch_bounds__(256) void softmax_rows(u16* __restrict__ SP) {
  const size_t base = ((size_t)blockIdx.y * 2048 + blockIdx.x) * 2048;
  u16* p = SP + base;
  const int t = threadIdx.x;
  __shared__ float red[4];

  uint4 u = ((const uint4*)p)[t];  // 8 bf16 per thread
  unsigned int uu[4] = {u.x, u.y, u.z, u.w};
  float f[8];
#pragma unroll
  for (int j = 0; j < 4; ++j) {
    f[2 * j] = bf2f(uu[j] & 0xffffu);
    f[2 * j + 1] = __builtin_bit_cast(float, uu[j] & 0xffff0000u);
  }
  float mx = f[0];
#pragma unroll
  for (int i = 1; i < 8; ++i) mx = fmaxf(mx, f[i]);
#pragma unroll
  for (int o = 32; o; o >>= 1) mx = fmaxf(mx, __shfl_xor(mx, o, 64));
  if ((t & 63) == 0) red[t >> 6] = mx;
  __syncthreads();
  mx = fmaxf(fmaxf(red[0], red[1]), fmaxf(red[2], red[3]));
  __syncthreads();

  float e[8];
  float sum = 0.f;
#pragma unroll
  for (int i = 0; i < 8; ++i) {
    e[i] = __expf(f[i] - mx);
    sum += e[i];
  }
#pragma unroll
  for (int o = 32; o; o >>= 1) sum += __shfl_xor(sum, o, 64);
  if ((t & 63) == 0) red[t >> 6] = sum;
  __syncthreads();
  sum = red[0] + red[1] + red[2] + red[3];
  const float inv = 1.0f / sum;

  uint4 ov;
  unsigned int w0[4];
#pragma unroll
  for (int j = 0; j < 4; ++j) {
    unsigned int lo = f2bf(e[2 * j] * inv);
    unsigned int hi = f2bf(e[2 * j + 1] * inv);
    w0[j] = lo | (hi << 16);
  }
  ov.x = w0[0];
  ov.y = w0[1];
  ov.z = w0[2];
  ov.w = w0[3];
  ((uint4*)p)[t] = ov;
}

// ---------------------------------------------------------------------------
extern "C" void kernel_launch(void* const* d_in, const int* in_sizes, int n_in,
                              void* d_out, int out_size, void* d_ws,
                              size_t ws_size, hipStream_t stream) {
  const float* x = (const float*)d_in[0];
  const float* Wq = (const float*)d_in[1];
  const float* bq = (const float*)d_in[2];
  const float* Wk = (const float*)d_in[3];
  const float* bk = (const float*)d_in[4];
  const float* Wv = (const float*)d_in[5];
  const float* bv = (const float*)d_in[6];
  float* out = (float*)d_out;
  char* ws = (char*)d_ws;

  u16* xb = (u16*)ws;                    // 16 MiB [8192][1024]
  u16* Wt = (u16*)(ws + 16777216);       // 6 MiB  [3072][1024]
  u16* Qb = (u16*)(ws + 23068672);       // 16 MiB [8192][1024]
  u16* Kb = Qb + 8388608;                // 16 MiB
  u16* Vt = Kb + 8388608;                // 16 MiB [4][1024][2048]
  u16* SP = Vt + 8388608;                // 32 MiB [4][2048][2048]

  // 1) dtype prep
  cvt_x<<<8192, 256, 0, stream>>>(x, xb);
  cvt_wt<<<dim3(32, 32, 3), dim3(32, 32), 0, stream>>>(Wq, Wk, Wv, Wt);

  // 2) fused QKV projection (N=3072; Q scaled 1/32 in epilogue)
  gemm8x<0><<<dim3(12, 32, 1), 512, 0, stream>>>(
      xb, Wt, bq, bk, bv, Qb, Kb, Vt, 1024, 0, 0, 0, 0);

  // 3) scores = Qs . K^T  (bf16 out, per batch)
  gemm8x<2><<<dim3(8, 8, 4), 512, 0, stream>>>(
      Qb, Kb, nullptr, nullptr, nullptr, SP, nullptr, nullptr, 1024, 2048,
      2097152LL, 2097152LL, 4194304LL);

  // 4) softmax in place
  softmax_rows<<<dim3(2048, 4), 256, 0, stream>>>(SP);

  // 5) out = P . V   (A = P [2048][2048], Bt = Vt [1024][2048])
  gemm2v<<<dim3(4, 16, 4), 512, 0, stream>>>(
      SP, Vt, out, 2048, 1024, 4194304LL, 2097152LL, 2097152LL);
}

// Round 8
// 175.842 us; speedup vs baseline: 1.0296x; 1.0066x over previous
//
#include <hip/hip_runtime.h>
#include <hip/hip_bf16.h>

typedef __attribute__((ext_vector_type(8))) short bf16x8;
typedef __attribute__((ext_vector_type(4))) float f32x4;
typedef unsigned short u16;

__device__ __forceinline__ u16 f2bf(float f) {
  unsigned int u = __builtin_bit_cast(unsigned int, f);
  u += 0x7fffu + ((u >> 16) & 1u);
  return (u16)(u >> 16);
}
__device__ __forceinline__ float bf2f(unsigned int h) {
  unsigned int u = h << 16;
  return __builtin_bit_cast(float, u);
}

__device__ __forceinline__ void gload_lds16(const void* g, void* l) {
  __builtin_amdgcn_global_load_lds(
      (const __attribute__((address_space(1))) void*)g,
      (__attribute__((address_space(3))) void*)l, 16, 0, 0);
}

#define BAR() __builtin_amdgcn_s_barrier()
#define VMC(N) asm volatile("s_waitcnt vmcnt(%0)" ::"n"(N) : "memory")

// ---------------------------------------------------------------------------
// Reg-pipelined 256x256 NT GEMM (scores). C[m][n]=sum_k A[m][k]*Bt[n][k].
// 512 thr = 8 waves (2 wr x 4 wc); per-wave 128x64 interleaved stripes.
// See r6/r7 notes. EPI 2: bf16 row-major out.
// ---------------------------------------------------------------------------
template <int EPI>
__global__ __launch_bounds__(512, 2) void gemm8x(
    const u16* __restrict__ Abase, const u16* __restrict__ Btbase,
    const float* __restrict__ bq, const float* __restrict__ bk,
    const float* __restrict__ bv, void* __restrict__ out0,
    void* __restrict__ out1, void* __restrict__ out2, int Kd, int ldc,
    long long sAz, long long sBz, long long sCz) {
  constexpr int HSZ = 16384;      // half: 128 rows x 64 k x 2B
  constexpr int BUFSZ = 4 * HSZ;  // A0,A1,B0,B1
  __shared__ char lds[2 * BUFSZ];

  const int tid = threadIdx.x;
  const int w = tid >> 6, l = tid & 63;
  const int wr = w >> 2, wc = w & 3;
  const int lq = l >> 4, lr = l & 15;
  const int bm = blockIdx.y * 256, bn = blockIdx.x * 256;
  const int z = blockIdx.z;
  const u16* A = Abase + (size_t)z * sAz;
  const u16* Bt = Btbase + (size_t)z * sBz;
  const int NTk = Kd >> 6;

  const int kbp = ((tid & 7) ^ ((tid >> 3) & 7)) * 8;
  const int drow = tid >> 3;
  const u16* gA[2][2];
  const u16* gB[2][2];
#pragma unroll
  for (int h = 0; h < 2; ++h)
#pragma unroll
    for (int u = 0; u < 2; ++u) {
      gA[h][u] = A + (size_t)(bm + h * 128 + u * 64 + drow) * Kd + kbp;
      gB[h][u] = Bt + (size_t)(bn + h * 128 + u * 64 + drow) * Kd + kbp;
    }

  auto stageA = [&](int buf, int h, int kt) {
    char* d = lds + buf * BUFSZ + h * HSZ + tid * 16;
    gload_lds16(gA[h][0] + kt * 64, d);
    gload_lds16(gA[h][1] + kt * 64, d + 8192);
  };
  auto stageB = [&](int buf, int h, int kt) {
    char* d = lds + buf * BUFSZ + (2 + h) * HSZ + tid * 16;
    gload_lds16(gB[h][0] + kt * 64, d);
    gload_lds16(gB[h][1] + kt * 64, d + 8192);
  };

  const int rA = wr * 64 + lr;
  const int rB = wc * 32 + lr;
  int aoff[2], boff[2];
#pragma unroll
  for (int kh = 0; kh < 2; ++kh) {
    aoff[kh] = rA * 128 + (((kh * 4 + lq) ^ (rA & 7)) << 4);
    boff[kh] = rB * 128 + (((kh * 4 + lq) ^ (rB & 7)) << 4);
  }

  f32x4 acc[2][4][2][2] = {};  // [mq][mf][nq][nf]
  bf16x8 aE[2][4], aO[2][4];
  bf16x8 bb[2][2][2];

#define RD_AE(BUF)                                                        \
  {                                                                       \
    const char* p_ = lds + (BUF)*BUFSZ;                                   \
    _Pragma("unroll") for (int kh = 0; kh < 2; ++kh)                      \
        _Pragma("unroll") for (int mf = 0; mf < 4; ++mf) aE[kh][mf] =     \
            *(const bf16x8*)(p_ + aoff[kh] + mf * 2048);                  \
  }
#define RD_AO(BUF)                                                        \
  {                                                                       \
    const char* p_ = lds + (BUF)*BUFSZ + HSZ;                             \
    _Pragma("unroll") for (int kh = 0; kh < 2; ++kh)                      \
        _Pragma("unroll") for (int mf = 0; mf < 4; ++mf) aO[kh][mf] =     \
            *(const bf16x8*)(p_ + aoff[kh] + mf * 2048);                  \
  }
#define RD_B(BUF, NQ)                                                     \
  {                                                                       \
    const char* p_ = lds + (BUF)*BUFSZ + (2 + (NQ)) * HSZ;                \
    _Pragma("unroll") for (int kh = 0; kh < 2; ++kh)                      \
        _Pragma("unroll") for (int nf = 0; nf < 2; ++nf) bb[NQ][kh][nf] = \
            *(const bf16x8*)(p_ + boff[kh] + nf * 2048);                  \
  }
#define MMAQ(MQ, NQ, ASET)                                                    \
  {                                                                           \
    __builtin_amdgcn_s_setprio(1);                                            \
    _Pragma("unroll") for (int kh = 0; kh < 2; ++kh)                          \
        _Pragma("unroll") for (int mf = 0; mf < 4; ++mf)                      \
            _Pragma("unroll") for (int nf = 0; nf < 2; ++nf) acc[MQ][mf][NQ]  \
                [nf] = __builtin_amdgcn_mfma_f32_16x16x32_bf16(               \
                    ASET[kh][mf], bb[NQ][kh][nf], acc[MQ][mf][NQ][nf], 0, 0,  \
                    0);                                                       \
    __builtin_amdgcn_s_setprio(0);                                            \
  }

  stageA(0, 0, 0);
  stageB(0, 0, 0);
  stageB(0, 1, 0);
  stageA(0, 1, 0);
  stageA(1, 0, 1);
  stageB(1, 0, 1);
  stageB(1, 1, 1);
  VMC(6);
  BAR();

  for (int t = 0; t < NTk; ++t) {
    const int buf = t & 1;
    const bool deep = (t + 2 < NTk);
    if (deep) VMC(6); else VMC(0);
    RD_AE(buf);
    RD_B(buf, 0);
    RD_B(buf, 1);
    if (t + 1 < NTk) stageA(buf ^ 1, 1, t + 1);
    BAR();
    MMAQ(0, 0, aE);
    if (deep) VMC(6); else VMC(0);
    RD_AO(buf);
    if (deep) stageA(buf, 0, t + 2);
    BAR();
    MMAQ(0, 1, aE);
    if (deep) VMC(6); else VMC(0);
    if (deep) stageB(buf, 0, t + 2);
    BAR();
    MMAQ(1, 1, aO);
    if (deep) VMC(6); else VMC(0);
    if (deep) stageB(buf, 1, t + 2);
    BAR();
    MMAQ(1, 0, aO);
  }

  // epilogue (EPI==2 path used). C/D frag: col=lane&15, row=(lane>>4)*4+e
  u16* C = (u16*)out0 + (size_t)z * sCz;
#pragma unroll
  for (int nq = 0; nq < 2; ++nq)
#pragma unroll
    for (int nf = 0; nf < 2; ++nf) {
      const int col = bn + wc * 32 + nq * 128 + nf * 16 + lr;
#pragma unroll
      for (int mq = 0; mq < 2; ++mq)
#pragma unroll
        for (int mf = 0; mf < 4; ++mf) {
          const int row = bm + wr * 64 + mq * 128 + mf * 16 + lq * 4;
#pragma unroll
          for (int e = 0; e < 4; ++e)
            C[(size_t)(row + e) * ldc + col] = f2bf(acc[mq][mf][nq][nf][e]);
        }
    }
#undef RD_AE
#undef RD_AO
#undef RD_B
#undef MMAQ
}

// ---------------------------------------------------------------------------
// Reg-pipelined 128x256 NT GEMM (proj + PV). 2 phases/K-tile. A dbuf
// (2x16KB) + B 3-slot ring (3x32KB) = 128KB. Per-wave 64x64 (2 wr x 4 wc).
// ph0: all 16 frag reads + stage B(t+2) [pre-BAR]; BAR; mma(kh0).
// ph1: VMC(4) [drains A(t+1),B(t+1); leaves B(t+2)]; BAR; stage A(t+2)
// [post-BAR: 1-barrier W-A-R margin on the A dbuf]; mma(kh1).
// EPI 0: fused QKV proj (Q:*1/32+bq, K:+bk, V:+bv transposed to Vt)
// EPI 3: f32 row-major out (final).
// ---------------------------------------------------------------------------
template <int EPI>
__global__ __launch_bounds__(512, 2) void gemm2t(
    const u16* __restrict__ Abase, const u16* __restrict__ Btbase,
    const float* __restrict__ bq, const float* __restrict__ bk,
    const float* __restrict__ bv, void* __restrict__ out0,
    void* __restrict__ out1, void* __restrict__ out2, int Kd, int ldc,
    long long sAz, long long sBz, long long sCz) {
  constexpr int ASZ = 16384;
  constexpr int BSZ = 32768;
  constexpr int BBASE = 2 * ASZ;
  __shared__ char lds[2 * ASZ + 3 * BSZ];

  const int tid = threadIdx.x;
  const int w = tid >> 6, l = tid & 63;
  const int wr = w >> 2, wc = w & 3;
  const int lq = l >> 4, lr = l & 15;
  const int bm = blockIdx.y * 128, bn = blockIdx.x * 256;
  const int z = blockIdx.z;
  const u16* A = Abase + (size_t)z * sAz;
  const u16* Bt = Btbase + (size_t)z * sBz;
  const int NT = Kd >> 6;

  const int kbp = ((tid & 7) ^ ((tid >> 3) & 7)) * 8;
  const int drow = tid >> 3;
  const u16* gA[2];
  const u16* gB[4];
#pragma unroll
  for (int u = 0; u < 2; ++u)
    gA[u] = A + (size_t)(bm + u * 64 + drow) * Kd + kbp;
#pragma unroll
  for (int u = 0; u < 4; ++u)
    gB[u] = Bt + (size_t)(bn + u * 64 + drow) * Kd + kbp;

  auto stageA = [&](int kt) {
    char* d = lds + (kt & 1) * ASZ + tid * 16;
#pragma unroll
    for (int u = 0; u < 2; ++u) gload_lds16(gA[u] + kt * 64, d + u * 8192);
  };
  auto stageB = [&](int kt) {
    char* d = lds + BBASE + (kt % 3) * BSZ + tid * 16;
#pragma unroll
    for (int u = 0; u < 4; ++u) gload_lds16(gB[u] + kt * 64, d + u * 8192);
  };

  const int rA = wr * 64 + lr;
  const int rB0 = wc * 64 + lr;
  int aoff[2];
#pragma unroll
  for (int kh = 0; kh < 2; ++kh)
    aoff[kh] = rA * 128 + (((kh * 4 + lq) ^ (rA & 7)) << 4);

  f32x4 acc[4][2][2] = {};   // [mf][nh][nf]
  bf16x8 a[2][4];            // [kh][mf]
  bf16x8 bb[2][2][2];        // [nh][kh][nf]

  auto rdA = [&](int kt) {
    const char* p = lds + (kt & 1) * ASZ;
#pragma unroll
    for (int kh = 0; kh < 2; ++kh)
#pragma unroll
      for (int mf = 0; mf < 4; ++mf)
        a[kh][mf] = *(const bf16x8*)(p + aoff[kh] + mf * 2048);
  };
  auto rdB = [&](int kt) {
    const char* p = lds + BBASE + (kt % 3) * BSZ;
#pragma unroll
    for (int nh = 0; nh < 2; ++nh) {
      const int rB = rB0 + nh * 32;
#pragma unroll
      for (int kh = 0; kh < 2; ++kh) {
        const int o = rB * 128 + (((kh * 4 + lq) ^ (rB & 7)) << 4);
#pragma unroll
        for (int nf = 0; nf < 2; ++nf)
          bb[nh][kh][nf] = *(const bf16x8*)(p + o + nf * 2048);
      }
    }
  };
  auto mma = [&](int kh) {
    __builtin_amdgcn_s_setprio(1);
#pragma unroll
    for (int nh = 0; nh < 2; ++nh)
#pragma unroll
      for (int mf = 0; mf < 4; ++mf)
#pragma unroll
        for (int nf = 0; nf < 2; ++nf)
          acc[mf][nh][nf] = __builtin_amdgcn_mfma_f32_16x16x32_bf16(
              a[kh][mf], bb[nh][kh][nf], acc[mf][nh][nf], 0, 0, 0);
    __builtin_amdgcn_s_setprio(0);
  };

  stageB(0);
  stageA(0);
  stageB(1);
  stageA(1);
  VMC(6);
  BAR();

  for (int t = 0; t < NT; ++t) {
    // ph0
    rdA(t);
    rdB(t);
    if (t + 2 < NT) stageB(t + 2);
    BAR();
    mma(0);
    // ph1
    if (t + 2 < NT) VMC(4); else VMC(0);
    BAR();
    if (t + 2 < NT) stageA(t + 2);
    mma(1);
  }

  // epilogue. C/D frag: col = lane&15, row = (lane>>4)*4 + e
  if constexpr (EPI == 0) {
    const int mat = bn >> 10;  // uniform per block (256 | 1024)
    const float sc = (mat == 0) ? 0.03125f : 1.0f;
    const float* bias = (mat == 0) ? bq : (mat == 1 ? bk : bv);
    u16* Q = (u16*)out0;
    u16* K = (u16*)out1;
    u16* V = (u16*)out2;
#pragma unroll
    for (int nh = 0; nh < 2; ++nh)
#pragma unroll
      for (int nf = 0; nf < 2; ++nf) {
        const int oc = (bn + wc * 64 + nh * 32 + nf * 16 + lr) & 1023;
        const float bb2 = bias[oc];
#pragma unroll
        for (int mf = 0; mf < 4; ++mf) {
          const int row = bm + wr * 64 + mf * 16 + lq * 4;
          if (mat < 2) {
            u16* dst = (mat == 0) ? Q : K;
#pragma unroll
            for (int e = 0; e < 4; ++e)
              dst[(size_t)(row + e) * 1024 + oc] =
                  f2bf((acc[mf][nh][nf][e] + bb2) * sc);
          } else {
            const int bz = row >> 11, sdx = row & 2047;
            ushort4 pk;
            pk.x = f2bf(acc[mf][nh][nf][0] + bb2);
            pk.y = f2bf(acc[mf][nh][nf][1] + bb2);
            pk.z = f2bf(acc[mf][nh][nf][2] + bb2);
            pk.w = f2bf(acc[mf][nh][nf][3] + bb2);
            *(ushort4*)&V[((size_t)bz * 1024 + oc) * 2048 + sdx] = pk;
          }
        }
      }
  } else {
    float* C = (float*)out0 + (size_t)z * sCz;
#pragma unroll
    for (int nh = 0; nh < 2; ++nh)
#pragma unroll
      for (int nf = 0; nf < 2; ++nf) {
        const int col = bn + wc * 64 + nh * 32 + nf * 16 + lr;
#pragma unroll
        for (int mf = 0; mf < 4; ++mf) {
          const int row = bm + wr * 64 + mf * 16 + lq * 4;
#pragma unroll
          for (int e = 0; e < 4; ++e)
            C[(size_t)(row + e) * ldc + col] = acc[mf][nh][nf][e];
        }
      }
  }
}

// ---------------------------------------------------------------------------
__global__ __launch_bounds__(256) void cvt_x(const float* __restrict__ in,
                                             u16* __restrict__ out) {
  const int i = blockIdx.x * 256 + threadIdx.x;
  const float4 v = ((const float4*)in)[i];
  ushort4 o;
  o.x = f2bf(v.x);
  o.y = f2bf(v.y);
  o.z = f2bf(v.z);
  o.w = f2bf(v.w);
  ((ushort4*)out)[i] = o;
}

// W [1024 in][1024 out] f32 -> Wt [1024 out][1024 in] bf16, z selects q/k/v
__global__ void cvt_wt(const float* __restrict__ Wq,
                       const float* __restrict__ Wk,
                       const float* __restrict__ Wv, u16* __restrict__ Wt) {
  __shared__ float s[32][33];
  const float* W = blockIdx.z == 0 ? Wq : (blockIdx.z == 1 ? Wk : Wv);
  u16* O = Wt + (size_t)blockIdx.z * 1048576;
  const int k0 = blockIdx.y * 32, n0 = blockIdx.x * 32;
  s[threadIdx.y][threadIdx.x] =
      W[(size_t)(k0 + threadIdx.y) * 1024 + n0 + threadIdx.x];
  __syncthreads();
  O[(size_t)(n0 + threadIdx.y) * 1024 + k0 + threadIdx.x] =
      f2bf(s[threadIdx.x][threadIdx.y]);
}

// in-place row softmax over bf16 [4][2048][2048]; one block per row
__global__ __launch_bounds__(256) void softmax_rows(u16* __restrict__ SP) {
  const size_t base = ((size_t)blockIdx.y * 2048 + blockIdx.x) * 2048;
  u16* p = SP + base;
  const int t = threadIdx.x;
  __shared__ float red[4];

  uint4 u = ((const uint4*)p)[t];  // 8 bf16 per thread
  unsigned int uu[4] = {u.x, u.y, u.z, u.w};
  float f[8];
#pragma unroll
  for (int j = 0; j < 4; ++j) {
    f[2 * j] = bf2f(uu[j] & 0xffffu);
    f[2 * j + 1] = __builtin_bit_cast(float, uu[j] & 0xffff0000u);
  }
  float mx = f[0];
#pragma unroll
  for (int i = 1; i < 8; ++i) mx = fmaxf(mx, f[i]);
#pragma unroll
  for (int o = 32; o; o >>= 1) mx = fmaxf(mx, __shfl_xor(mx, o, 64));
  if ((t & 63) == 0) red[t >> 6] = mx;
  __syncthreads();
  mx = fmaxf(fmaxf(red[0], red[1]), fmaxf(red[2], red[3]));
  __syncthreads();

  float e[8];
  float sum = 0.f;
#pragma unroll
  for (int i = 0; i < 8; ++i) {
    e[i] = __expf(f[i] - mx);
    sum += e[i];
  }
#pragma unroll
  for (int o = 32; o; o >>= 1) sum += __shfl_xor(sum, o, 64);
  if ((t & 63) == 0) red[t >> 6] = sum;
  __syncthreads();
  sum = red[0] + red[1] + red[2] + red[3];
  const float inv = 1.0f / sum;

  uint4 ov;
  unsigned int w0[4];
#pragma unroll
  for (int j = 0; j < 4; ++j) {
    unsigned int lo = f2bf(e[2 * j] * inv);
    unsigned int hi = f2bf(e[2 * j + 1] * inv);
    w0[j] = lo | (hi << 16);
  }
  ov.x = w0[0];
  ov.y = w0[1];
  ov.z = w0[2];
  ov.w = w0[3];
  ((uint4*)p)[t] = ov;
}

// ---------------------------------------------------------------------------
extern "C" void kernel_launch(void* const* d_in, const int* in_sizes, int n_in,
                              void* d_out, int out_size, void* d_ws,
                              size_t ws_size, hipStream_t stream) {
  const float* x = (const float*)d_in[0];
  const float* Wq = (const float*)d_in[1];
  const float* bq = (const float*)d_in[2];
  const float* Wk = (const float*)d_in[3];
  const float* bk = (const float*)d_in[4];
  const float* Wv = (const float*)d_in[5];
  const float* bv = (const float*)d_in[6];
  float* out = (float*)d_out;
  char* ws = (char*)d_ws;

  u16* xb = (u16*)ws;                    // 16 MiB [8192][1024]
  u16* Wt = (u16*)(ws + 16777216);       // 6 MiB  [3072][1024]
  u16* Qb = (u16*)(ws + 23068672);       // 16 MiB [8192][1024]
  u16* Kb = Qb + 8388608;                // 16 MiB
  u16* Vt = Kb + 8388608;                // 16 MiB [4][1024][2048]
  u16* SP = Vt + 8388608;                // 32 MiB [4][2048][2048]

  // 1) dtype prep
  cvt_x<<<8192, 256, 0, stream>>>(x, xb);
  cvt_wt<<<dim3(32, 32, 3), dim3(32, 32), 0, stream>>>(Wq, Wk, Wv, Wt);

  // 2) fused QKV projection: 128x256 tile, grid 12x64 = 768 = 3/CU balanced
  gemm2t<0><<<dim3(12, 64, 1), 512, 0, stream>>>(
      xb, Wt, bq, bk, bv, Qb, Kb, Vt, 1024, 0, 0, 0, 0);

  // 3) scores = Qs . K^T  (bf16 out, per batch; 256 blocks = 1/CU)
  gemm8x<2><<<dim3(8, 8, 4), 512, 0, stream>>>(
      Qb, Kb, nullptr, nullptr, nullptr, SP, nullptr, nullptr, 1024, 2048,
      2097152LL, 2097152LL, 4194304LL);

  // 4) softmax in place
  softmax_rows<<<dim3(2048, 4), 256, 0, stream>>>(SP);

  // 5) out = P . V  (128x256 tile, 256 blocks = 1/CU)
  gemm2t<3><<<dim3(4, 16, 4), 512, 0, stream>>>(
      SP, Vt, nullptr, nullptr, nullptr, out, nullptr, nullptr, 2048, 1024,
      4194304LL, 2097152LL, 2097152LL);
}

// Round 9
// 175.816 us; speedup vs baseline: 1.0298x; 1.0001x over previous
//
#include <hip/hip_runtime.h>
#include <hip/hip_bf16.h>

typedef __attribute__((ext_vector_type(8))) short bf16x8;
typedef __attribute__((ext_vector_type(4))) float f32x4;
typedef unsigned short u16;

__device__ __forceinline__ u16 f2bf(float f) {
  unsigned int u = __builtin_bit_cast(unsigned int, f);
  u += 0x7fffu + ((u >> 16) & 1u);
  return (u16)(u >> 16);
}
__device__ __forceinline__ float bf2f(unsigned int h) {
  unsigned int u = h << 16;
  return __builtin_bit_cast(float, u);
}

__device__ __forceinline__ void gload_lds16(const void* g, void* l) {
  __builtin_amdgcn_global_load_lds(
      (const __attribute__((address_space(1))) void*)g,
      (__attribute__((address_space(3))) void*)l, 16, 0, 0);
}

#define BAR() __builtin_amdgcn_s_barrier()
#define VMC(N) asm volatile("s_waitcnt vmcnt(%0)" ::"n"(N) : "memory")

// ---------------------------------------------------------------------------
// 128x128-tile 2-phase counted-vmcnt NT GEMM, 2 blocks/CU co-resident.
// C[m][n] = sum_k A[m][k]*Bt[n][k].  256 thr = 4 waves (2 wr x 2 wc),
// per-wave 64x64.  K-tile 64.  LDS 80KB: A dbuf (2x16K) + B 3-ring (3x16K)
// -> two blocks fit in 160KB/CU; independent blocks fill each other's
// barrier/vmcnt stalls (m114 overlap).  Schedule per K-tile t (r8 constants):
//  ph0: rdA(t)[8] + rdB(t)[8]; stageB(t+2)[4, ring slot sealed 2 BARs ago];
//       BAR; mma(kh0)[16 MFMA]
//  ph1: VMC(4) [drains A(t+1),B(t+1); leaves B(t+2)]; BAR; stageA(t+2)
//       [dbuf slot sealed 2 BARs ago]; mma(kh1)[16]
// Swizzle: LDS[row][b16] = global[row][b16 ^ (row&7)]; reads same XOR
// (0 bank conflicts, measured r1-r8).
// EPI 0: fused QKV proj (Q:*1/32+bq, K:+bk, V:+bv transposed to Vt)
// EPI 2: bf16 row-major out (scores)   EPI 3: f32 row-major out (final)
// ---------------------------------------------------------------------------
template <int EPI>
__global__ __launch_bounds__(256) void gemm2s(
    const u16* __restrict__ Abase, const u16* __restrict__ Btbase,
    const float* __restrict__ bq, const float* __restrict__ bk,
    const float* __restrict__ bv, void* __restrict__ out0,
    void* __restrict__ out1, void* __restrict__ out2, int Kd, int ldc,
    long long sAz, long long sBz, long long sCz) {
  constexpr int ASZ = 16384;   // A K-tile: 128 rows x 64 k x 2B
  constexpr int BSZ = 16384;   // B K-tile: 128 rows x 64 k x 2B
  constexpr int BBASE = 2 * ASZ;
  __shared__ char lds[2 * ASZ + 3 * BSZ];  // 81920 B

  const int tid = threadIdx.x;
  const int w = tid >> 6, l = tid & 63;
  const int wr = w >> 1, wc = w & 1;
  const int lq = l >> 4, lr = l & 15;
  const int bm = blockIdx.y * 128, bn = blockIdx.x * 128;
  const int z = blockIdx.z;
  const u16* A = Abase + (size_t)z * sAz;
  const u16* Bt = Btbase + (size_t)z * sBz;
  const int NT = Kd >> 6;

  // staging: dest byte tid*16 + u*4096 (u=0..3); dest row = u*32 + (tid>>3);
  // source 16B col-block pre-swizzled: kb' = (tid&7) ^ (row&7)
  const int kbp = ((tid & 7) ^ ((tid >> 3) & 7)) * 8;
  const int drow = tid >> 3;
  const u16* gA[4];
  const u16* gB[4];
#pragma unroll
  for (int u = 0; u < 4; ++u) {
    gA[u] = A + (size_t)(bm + u * 32 + drow) * Kd + kbp;
    gB[u] = Bt + (size_t)(bn + u * 32 + drow) * Kd + kbp;
  }

  auto stageA = [&](int kt) {  // 4 gloads
    char* d = lds + (kt & 1) * ASZ + tid * 16;
#pragma unroll
    for (int u = 0; u < 4; ++u) gload_lds16(gA[u] + kt * 64, d + u * 4096);
  };
  auto stageB = [&](int kt) {  // 4 gloads
    char* d = lds + BBASE + (kt % 3) * BSZ + tid * 16;
#pragma unroll
    for (int u = 0; u < 4; ++u) gload_lds16(gB[u] + kt * 64, d + u * 4096);
  };

  const int rA = wr * 64 + lr;
  const int rB0 = wc * 64 + lr;
  int aoff[2];
#pragma unroll
  for (int kh = 0; kh < 2; ++kh)
    aoff[kh] = rA * 128 + (((kh * 4 + lq) ^ (rA & 7)) << 4);

  f32x4 acc[4][2][2] = {};   // [mf][nh][nf]
  bf16x8 a[2][4];            // [kh][mf]
  bf16x8 bb[2][2][2];        // [nh][kh][nf]

  auto rdA = [&](int kt) {
    const char* p = lds + (kt & 1) * ASZ;
#pragma unroll
    for (int kh = 0; kh < 2; ++kh)
#pragma unroll
      for (int mf = 0; mf < 4; ++mf)
        a[kh][mf] = *(const bf16x8*)(p + aoff[kh] + mf * 2048);
  };
  auto rdB = [&](int kt) {
    const char* p = lds + BBASE + (kt % 3) * BSZ;
#pragma unroll
    for (int nh = 0; nh < 2; ++nh) {
      const int rB = rB0 + nh * 32;
#pragma unroll
      for (int kh = 0; kh < 2; ++kh) {
        const int o = rB * 128 + (((kh * 4 + lq) ^ (rB & 7)) << 4);
#pragma unroll
        for (int nf = 0; nf < 2; ++nf)
          bb[nh][kh][nf] = *(const bf16x8*)(p + o + nf * 2048);
      }
    }
  };
  auto mma = [&](int kh) {
    __builtin_amdgcn_s_setprio(1);
#pragma unroll
    for (int nh = 0; nh < 2; ++nh)
#pragma unroll
      for (int mf = 0; mf < 4; ++mf)
#pragma unroll
        for (int nf = 0; nf < 2; ++nf)
          acc[mf][nh][nf] = __builtin_amdgcn_mfma_f32_16x16x32_bf16(
              a[kh][mf], bb[nh][kh][nf], acc[mf][nh][nf], 0, 0, 0);
    __builtin_amdgcn_s_setprio(0);
  };

  // prologue: B(0), A(0), B(1), A(1); VMC(8) -> tile0 landed
  stageB(0);
  stageA(0);
  stageB(1);
  stageA(1);
  VMC(8);
  BAR();

  for (int t = 0; t < NT; ++t) {
    // ph0
    rdA(t);
    rdB(t);
    if (t + 2 < NT) stageB(t + 2);
    BAR();
    mma(0);
    // ph1
    if (t + 2 < NT) VMC(4); else VMC(0);
    BAR();
    if (t + 2 < NT) stageA(t + 2);
    mma(1);
  }

  // epilogue. C/D frag: col = lane&15, row = (lane>>4)*4 + e  [m89]
  if constexpr (EPI == 0) {
    const int mat = bn >> 10;  // uniform per block (128 | 1024)
    const float sc = (mat == 0) ? 0.03125f : 1.0f;
    const float* bias = (mat == 0) ? bq : (mat == 1 ? bk : bv);
    u16* Q = (u16*)out0;
    u16* K = (u16*)out1;
    u16* V = (u16*)out2;
#pragma unroll
    for (int nh = 0; nh < 2; ++nh)
#pragma unroll
      for (int nf = 0; nf < 2; ++nf) {
        const int oc = (bn + wc * 64 + nh * 32 + nf * 16 + lr) & 1023;
        const float bb2 = bias[oc];
#pragma unroll
        for (int mf = 0; mf < 4; ++mf) {
          const int row = bm + wr * 64 + mf * 16 + lq * 4;
          if (mat < 2) {
            u16* dst = (mat == 0) ? Q : K;
#pragma unroll
            for (int e = 0; e < 4; ++e)
              dst[(size_t)(row + e) * 1024 + oc] =
                  f2bf((acc[mf][nh][nf][e] + bb2) * sc);
          } else {
            const int bz = row >> 11, sdx = row & 2047;
            ushort4 pk;
            pk.x = f2bf(acc[mf][nh][nf][0] + bb2);
            pk.y = f2bf(acc[mf][nh][nf][1] + bb2);
            pk.z = f2bf(acc[mf][nh][nf][2] + bb2);
            pk.w = f2bf(acc[mf][nh][nf][3] + bb2);
            *(ushort4*)&V[((size_t)bz * 1024 + oc) * 2048 + sdx] = pk;
          }
        }
      }
  } else if constexpr (EPI == 2) {
    u16* C = (u16*)out0 + (size_t)z * sCz;
#pragma unroll
    for (int nh = 0; nh < 2; ++nh)
#pragma unroll
      for (int nf = 0; nf < 2; ++nf) {
        const int col = bn + wc * 64 + nh * 32 + nf * 16 + lr;
#pragma unroll
        for (int mf = 0; mf < 4; ++mf) {
          const int row = bm + wr * 64 + mf * 16 + lq * 4;
#pragma unroll
          for (int e = 0; e < 4; ++e)
            C[(size_t)(row + e) * ldc + col] = f2bf(acc[mf][nh][nf][e]);
        }
      }
  } else {
    float* C = (float*)out0 + (size_t)z * sCz;
#pragma unroll
    for (int nh = 0; nh < 2; ++nh)
#pragma unroll
      for (int nf = 0; nf < 2; ++nf) {
        const int col = bn + wc * 64 + nh * 32 + nf * 16 + lr;
#pragma unroll
        for (int mf = 0; mf < 4; ++mf) {
          const int row = bm + wr * 64 + mf * 16 + lq * 4;
#pragma unroll
          for (int e = 0; e < 4; ++e)
            C[(size_t)(row + e) * ldc + col] = acc[mf][nh][nf][e];
        }
      }
  }
}

// ---------------------------------------------------------------------------
__global__ __launch_bounds__(256) void cvt_x(const float* __restrict__ in,
                                             u16* __restrict__ out) {
  const int i = blockIdx.x * 256 + threadIdx.x;
  const float4 v = ((const float4*)in)[i];
  ushort4 o;
  o.x = f2bf(v.x);
  o.y = f2bf(v.y);
  o.z = f2bf(v.z);
  o.w = f2bf(v.w);
  ((ushort4*)out)[i] = o;
}

// W [1024 in][1024 out] f32 -> Wt [1024 out][1024 in] bf16, z selects q/k/v
__global__ void cvt_wt(const float* __restrict__ Wq,
                       const float* __restrict__ Wk,
                       const float* __restrict__ Wv, u16* __restrict__ Wt) {
  __shared__ float s[32][33];
  const float* W = blockIdx.z == 0 ? Wq : (blockIdx.z == 1 ? Wk : Wv);
  u16* O = Wt + (size_t)blockIdx.z * 1048576;
  const int k0 = blockIdx.y * 32, n0 = blockIdx.x * 32;
  s[threadIdx.y][threadIdx.x] =
      W[(size_t)(k0 + threadIdx.y) * 1024 + n0 + threadIdx.x];
  __syncthreads();
  O[(size_t)(n0 + threadIdx.y) * 1024 + k0 + threadIdx.x] =
      f2bf(s[threadIdx.x][threadIdx.y]);
}

// in-place row softmax over bf16 [4][2048][2048]; one block per row
__global__ __launch_bounds__(256) void softmax_rows(u16* __restrict__ SP) {
  const size_t base = ((size_t)blockIdx.y * 2048 + blockIdx.x) * 2048;
  u16* p = SP + base;
  const int t = threadIdx.x;
  __shared__ float red[4];

  uint4 u = ((const uint4*)p)[t];  // 8 bf16 per thread
  unsigned int uu[4] = {u.x, u.y, u.z, u.w};
  float f[8];
#pragma unroll
  for (int j = 0; j < 4; ++j) {
    f[2 * j] = bf2f(uu[j] & 0xffffu);
    f[2 * j + 1] = __builtin_bit_cast(float, uu[j] & 0xffff0000u);
  }
  float mx = f[0];
#pragma unroll
  for (int i = 1; i < 8; ++i) mx = fmaxf(mx, f[i]);
#pragma unroll
  for (int o = 32; o; o >>= 1) mx = fmaxf(mx, __shfl_xor(mx, o, 64));
  if ((t & 63) == 0) red[t >> 6] = mx;
  __syncthreads();
  mx = fmaxf(fmaxf(red[0], red[1]), fmaxf(red[2], red[3]));
  __syncthreads();

  float e[8];
  float sum = 0.f;
#pragma unroll
  for (int i = 0; i < 8; ++i) {
    e[i] = __expf(f[i] - mx);
    sum += e[i];
  }
#pragma unroll
  for (int o = 32; o; o >>= 1) sum += __shfl_xor(sum, o, 64);
  if ((t & 63) == 0) red[t >> 6] = sum;
  __syncthreads();
  sum = red[0] + red[1] + red[2] + red[3];
  const float inv = 1.0f / sum;

  uint4 ov;
  unsigned int w0[4];
#pragma unroll
  for (int j = 0; j < 4; ++j) {
    unsigned int lo = f2bf(e[2 * j] * inv);
    unsigned int hi = f2bf(e[2 * j + 1] * inv);
    w0[j] = lo | (hi << 16);
  }
  ov.x = w0[0];
  ov.y = w0[1];
  ov.z = w0[2];
  ov.w = w0[3];
  ((uint4*)p)[t] = ov;
}

// ---------------------------------------------------------------------------
extern "C" void kernel_launch(void* const* d_in, const int* in_sizes, int n_in,
                              void* d_out, int out_size, void* d_ws,
                              size_t ws_size, hipStream_t stream) {
  const float* x = (const float*)d_in[0];
  const float* Wq = (const float*)d_in[1];
  const float* bq = (const float*)d_in[2];
  const float* Wk = (const float*)d_in[3];
  const float* bk = (const float*)d_in[4];
  const float* Wv = (const float*)d_in[5];
  const float* bv = (const float*)d_in[6];
  float* out = (float*)d_out;
  char* ws = (char*)d_ws;

  u16* xb = (u16*)ws;                    // 16 MiB [8192][1024]
  u16* Wt = (u16*)(ws + 16777216);       // 6 MiB  [3072][1024]
  u16* Qb = (u16*)(ws + 23068672);       // 16 MiB [8192][1024]
  u16* Kb = Qb + 8388608;                // 16 MiB
  u16* Vt = Kb + 8388608;                // 16 MiB [4][1024][2048]
  u16* SP = Vt + 8388608;                // 32 MiB [4][2048][2048]

  // 1) dtype prep
  cvt_x<<<8192, 256, 0, stream>>>(x, xb);
  cvt_wt<<<dim3(32, 32, 3), dim3(32, 32), 0, stream>>>(Wq, Wk, Wv, Wt);

  // 2) fused QKV projection: 128x128 tiles, grid 1536 = 3 rounds x 2/CU
  gemm2s<0><<<dim3(24, 64, 1), 256, 0, stream>>>(
      xb, Wt, bq, bk, bv, Qb, Kb, Vt, 1024, 0, 0, 0, 0);

  // 3) scores = Qs . K^T  (bf16 out; grid 1024 = 2 rounds x 2/CU)
  gemm2s<2><<<dim3(16, 16, 4), 256, 0, stream>>>(
      Qb, Kb, nullptr, nullptr, nullptr, SP, nullptr, nullptr, 1024, 2048,
      2097152LL, 2097152LL, 4194304LL);

  // 4) softmax in place
  softmax_rows<<<dim3(2048, 4), 256, 0, stream>>>(SP);

  // 5) out = P . V  (grid 512 = 1 round x 2/CU)
  gemm2s<3><<<dim3(8, 16, 4), 256, 0, stream>>>(
      SP, Vt, nullptr, nullptr, nullptr, out, nullptr, nullptr, 2048, 1024,
      4194304LL, 2097152LL, 2097152LL);
}